// Round 9
// baseline (241.201 us; speedup 1.0000x reference)
//
#include <hip/hip_runtime.h>

typedef unsigned short u16;
typedef __bf16 bf16;
typedef float f32x4 __attribute__((ext_vector_type(4)));
typedef bf16 bf16x8 __attribute__((ext_vector_type(8)));
typedef short s16x4 __attribute__((ext_vector_type(4)));
typedef u16 u16x4 __attribute__((ext_vector_type(4)));
typedef u16 u16x8 __attribute__((ext_vector_type(8)));

#define SEQ 2048
#define LOG2E 1.4426950408889634f

__device__ __forceinline__ u16 f2bf(float f) {
    return __builtin_bit_cast(u16, (bf16)f);
}
__device__ __forceinline__ float bf2f(u16 u) {
    unsigned int w = ((unsigned int)u) << 16;
    return __builtin_bit_cast(float, w);
}

// ---------------- cast f32 -> bf16 (vectorized) ----------------
__global__ __launch_bounds__(256) void cast_bf16_k(const float* __restrict__ in,
                                                   u16* __restrict__ out, int n4) {
    int i = blockIdx.x * 256 + threadIdx.x;
    int stride = gridDim.x * 256;
    for (; i < n4; i += stride) {
        float4 v = reinterpret_cast<const float4*>(in)[i];
        u16x4 o;
        o[0] = f2bf(v.x); o[1] = f2bf(v.y); o[2] = f2bf(v.z); o[3] = f2bf(v.w);
        reinterpret_cast<u16x4*>(out)[i] = o;
    }
}

// ---------------- transpose + cast: src f32 [R][C] -> dst bf16 [C][R] ----------------
__global__ __launch_bounds__(256) void transpose_cast_k(const float* __restrict__ src,
                                                        u16* __restrict__ dst, int R, int C) {
    __shared__ float t[64][65];
    int c0 = blockIdx.x * 64, r0 = blockIdx.y * 64;
    int tx = threadIdx.x & 63, ty = threadIdx.x >> 6;
#pragma unroll
    for (int i = 0; i < 16; ++i) {
        int r = ty + i * 4;
        t[r][tx] = src[(size_t)(r0 + r) * C + c0 + tx];
    }
    __syncthreads();
#pragma unroll
    for (int i = 0; i < 16; ++i) {
        int c = ty + i * 4;
        dst[(size_t)(c0 + c) * R + r0 + tx] = f2bf(t[tx][c]);
    }
}

// ---------------- GEMM partial: Cp[z][M,N](bf16) = A[M,kz] @ Bt[N,kz]^T ----------------
// 128x128 tile, BK=32, split-K (blockIdx.z), double-buffered LDS with prefetch,
// XOR-swizzled LDS slots (pre-swizzled gload_lds source + swizzled ds_read; rule #21).
__global__ __launch_bounds__(256) void gemm_bt_dbuf_k(const u16* __restrict__ A,
                                                      const u16* __restrict__ Bt,
                                                      u16* __restrict__ Cp,
                                                      int M, int N, int K) {
    __shared__ __align__(16) u16 As[2][128 * 32];
    __shared__ __align__(16) u16 Bs[2][128 * 32];
    int tid = threadIdx.x;
    int wave = tid >> 6, lane = tid & 63;
    int bm = blockIdx.y * 128, bn = blockIdx.x * 128;
    int z = blockIdx.z;
    int kt0 = z * (K >> 1), ktend = kt0 + (K >> 1);
    int wm = (wave >> 1) * 64, wn = (wave & 1) * 64;
    int g = lane >> 4, cidx = lane & 15;
    f32x4 acc[4][4] = {};

    // staging: LDS slot (srow, lane&3) holds global k-chunk (lane&3) ^ ((srow>>1)&3)
    int srow = lane >> 2;
    int skol = ((lane & 3) ^ ((srow >> 1) & 3)) * 8;
    // read: logical chunk g of row r lives at slot g ^ ((r_in16>>1)&3); r_in16 = cidx
    int sl8 = (g ^ ((cidx >> 1) & 3)) * 8;

#define STAGE(buf, kt)                                                                \
    {                                                                                 \
        _Pragma("unroll")                                                             \
        for (int j = 0; j < 2; ++j) {                                                 \
            const u16* gpa = A + (size_t)(bm + (wave * 2 + j) * 16 + srow) * K + (kt) + skol; \
            __builtin_amdgcn_global_load_lds(                                         \
                (__attribute__((address_space(1))) void*)gpa,                         \
                (__attribute__((address_space(3))) void*)&As[buf][(wave * 2 + j) * 512], \
                16, 0, 0);                                                            \
        }                                                                             \
        _Pragma("unroll")                                                             \
        for (int j = 0; j < 2; ++j) {                                                 \
            const u16* gpb = Bt + (size_t)(bn + (wave * 2 + j) * 16 + srow) * K + (kt) + skol; \
            __builtin_amdgcn_global_load_lds(                                         \
                (__attribute__((address_space(1))) void*)gpb,                         \
                (__attribute__((address_space(3))) void*)&Bs[buf][(wave * 2 + j) * 512], \
                16, 0, 0);                                                            \
        }                                                                             \
    }

    STAGE(0, kt0);
    asm volatile("s_waitcnt vmcnt(0)" ::: "memory");
    __syncthreads();

    int cur = 0;
#pragma unroll 1
    for (int kt = kt0; kt < ktend; kt += 32) {
        if (kt + 32 < ktend) STAGE(cur ^ 1, kt + 32);  // prefetch in flight across compute

        bf16x8 af[4], bfr[4];
#pragma unroll
        for (int mi = 0; mi < 4; ++mi)
            af[mi] = *reinterpret_cast<const bf16x8*>(&As[cur][(wm + mi * 16 + cidx) * 32 + sl8]);
#pragma unroll
        for (int ni = 0; ni < 4; ++ni)
            bfr[ni] = *reinterpret_cast<const bf16x8*>(&Bs[cur][(wn + ni * 16 + cidx) * 32 + sl8]);
#pragma unroll
        for (int mi = 0; mi < 4; ++mi)
#pragma unroll
            for (int ni = 0; ni < 4; ++ni)
                acc[mi][ni] = __builtin_amdgcn_mfma_f32_16x16x32_bf16(af[mi], bfr[ni], acc[mi][ni], 0, 0, 0);

        asm volatile("s_waitcnt vmcnt(0)" ::: "memory");
        __syncthreads();
        cur ^= 1;
    }
#undef STAGE

    u16* cbase = Cp + (size_t)z * M * N;
#pragma unroll
    for (int mi = 0; mi < 4; ++mi) {
#pragma unroll
        for (int r = 0; r < 4; ++r) {
            int row = bm + wm + mi * 16 + g * 4 + r;
            u16* cp = cbase + (size_t)row * N + bn + wn + cidx;
#pragma unroll
            for (int ni = 0; ni < 4; ++ni)
                cp[ni * 16] = f2bf(acc[mi][ni][r]);
        }
    }
}

// ---------------- sum two bf16 partials -> f32 ----------------
__global__ __launch_bounds__(256) void sum2_f32_k(const u16* __restrict__ a,
                                                  const u16* __restrict__ b,
                                                  float* __restrict__ out, int n8) {
    int i = blockIdx.x * 256 + threadIdx.x;
    if (i >= n8) return;
    u16x8 va = reinterpret_cast<const u16x8*>(a)[i];
    u16x8 vb = reinterpret_cast<const u16x8*>(b)[i];
    f32x4 lo, hi;
#pragma unroll
    for (int j = 0; j < 4; ++j) {
        lo[j] = bf2f(va[j]) + bf2f(vb[j]);
        hi[j] = bf2f(va[4 + j]) + bf2f(vb[4 + j]);
    }
    reinterpret_cast<f32x4*>(out)[i * 2] = lo;
    reinterpret_cast<f32x4*>(out)[i * 2 + 1] = hi;
}

// ---------------- RMSNorm + RoPE for Q and K heads (sums split-K partials) ----------------
// Q: pre-scaled by 0.125*log2(e) (exp2-base softmax), row-major [s][32*64]
// K: MFMA A-fragment order with PERMUTED key placement inside each 32-key group:
//   k32 -> phys (sub = bit2, row = (k32>>3)*4 + (k32&3)); this makes two QK 16-subs
//   concatenate into a K=32 PV B-fragment (lane g holds keys g*8..g*8+7).
__global__ __launch_bounds__(256) void norm_rope_k(const u16* __restrict__ p0,
                                                   const u16* __restrict__ p1,
                                                   const float* __restrict__ cosb,
                                                   const float* __restrict__ sinb,
                                                   const float* __restrict__ qw,
                                                   const float* __restrict__ kw,
                                                   u16* __restrict__ qn,
                                                   u16* __restrict__ kfrag) {
    int idx = blockIdx.x * 4 + (threadIdx.x >> 6);
    int lane = threadIdx.x & 63;
    int s = idx / 40, hh = idx - s * 40;
    size_t off = (hh < 32) ? ((size_t)s * 3072 + hh * 64 + lane)
                           : ((size_t)s * 3072 + 2048 + (hh - 32) * 64 + lane);
    float val = bf2f(p0[off]) + bf2f(p1[off]);
    float ss = val * val;
#pragma unroll
    for (int mm = 32; mm; mm >>= 1) ss += __shfl_xor(ss, mm);
    float w = (hh < 32) ? qw[lane] : kw[lane];
    float xn = val * rsqrtf(ss * (1.f / 64.f) + 1e-6f) * w;
    float part = __shfl_xor(xn, 32);
    float rot = (lane < 32) ? -part : part;
    float o = xn * cosb[s * 64 + lane] + rot * sinb[s * 64 + lane];
    if (hh < 32) {
        qn[(size_t)s * 2048 + hh * 64 + lane] = f2bf(o * (0.125f * LOG2E));
    } else {
        int h8 = hh - 32;
        int k32 = s & 31;
        int p32 = ((k32 >> 2) & 1) * 16 + ((k32 >> 3) << 2) + (k32 & 3);
        int p = (s & ~31) + p32;
        kfrag[(((size_t)h8 * 128 + (p >> 4)) << 10) + (lane >> 3) * 128 + (p & 15) * 8 + (lane & 7)] = f2bf(o);
    }
}

// ---------------- V in K=32 PV A-fragment order ----------------
// vfrag[kvh][kb32][dt][lane(g*16+cc)][i] = V[kb32*32 + g*8 + i][dt*16 + cc]
__global__ __launch_bounds__(256) void v_frag_k(const u16* __restrict__ p0,
                                                const u16* __restrict__ p1,
                                                u16* __restrict__ vfrag) {
    __shared__ float t[64][65];
    int s0 = blockIdx.x * 64;
    int h = blockIdx.y;
    int tx = threadIdx.x & 63, ty = threadIdx.x >> 6;
#pragma unroll
    for (int i = 0; i < 16; ++i) {
        int r = ty + i * 4;
        size_t off = (size_t)(s0 + r) * 3072 + 2560 + h * 64 + tx;
        t[r][tx] = bf2f(p0[off]) + bf2f(p1[off]);
    }
    __syncthreads();
    int dt = threadIdx.x >> 6, g = (threadIdx.x >> 4) & 3, cc = threadIdx.x & 15;
#pragma unroll
    for (int kb = 0; kb < 2; ++kb) {
        u16x8 o;
#pragma unroll
        for (int i = 0; i < 8; ++i) o[i] = f2bf(t[kb * 32 + g * 8 + i][dt * 16 + cc]);
        *reinterpret_cast<u16x8*>(
            &vfrag[((size_t)h * 64 + (s0 >> 5) + kb) * 2048 + dt * 512 + (size_t)(threadIdx.x & 63) * 8]) = o;
    }
}

// ---------------- Flash attention: dual-stream waves (32 q-rows) + GQA-group blocks ----------------
// block = (kvh, item); 4 waves = 4 q-heads of the group (shared K/V address stream -> L1 reuse).
// Each wave owns chunks c=2t (A) and c=2t+1 (B) over window w: two INDEPENDENT
// QK/softmax/PV chains per iteration (2x ILP, latency-bound fix) sharing K/V loads.
// A's trailing dead block self-masks (all keys > qrowA -> exp2 -> 0).
// item -> (t,w): t<16:1 window, <32:2, <48:3, else 4 (160 items/head, reversed: long first).
// NOTE: launch_bounds min-waves MUST stay <=4: (256,8) capped VGPR at 32 and
// spilled ~1.3 GB of scratch to HBM per dispatch (round-4 regression).
__global__ __launch_bounds__(256, 4) void attn_k(const u16* __restrict__ qn,
                                                 const u16* __restrict__ kfrag,
                                                 const u16* __restrict__ vfrag,
                                                 u16* __restrict__ obuf,
                                                 float* __restrict__ lbuf) {
    int kvh = blockIdx.x;
    int wave = threadIdx.x >> 6, lane = threadIdx.x & 63;
    int h = kvh * 4 + wave;
    int item = 159 - blockIdx.y;   // reversed: long windows first
    int t, w;
    if (item < 16)      { t = item;                   w = 0; }
    else if (item < 48) { t = 16 + ((item - 16) >> 1); w = (item - 16) & 1; }
    else if (item < 96) { int r = item - 48; int q = r / 3; t = 32 + q; w = r - 3 * q; }
    else                { t = 48 + ((item - 96) >> 2); w = (item - 96) & 3; }

    int qA0 = t * 32;          // chunk c=2t   rows [qA0, qA0+16)
    int qB0 = qA0 + 16;        // chunk c=2t+1 rows [qB0, qB0+16)
    int kv0 = w * 512;
    int nkB = qB0 + 16;
    int kvend = (kv0 + 512 < nkB) ? (kv0 + 512) : nkB;

    int g = lane >> 4, cc = lane & 15;
    int qrowA = qA0 + cc, qrowB = qB0 + cc;

    const size_t qoffA = (size_t)qrowA * 2048 + h * 64;
    const size_t qoffB = (size_t)qrowB * 2048 + h * 64;
    bf16x8 qa0 = *reinterpret_cast<const bf16x8*>(&qn[qoffA + g * 8]);
    bf16x8 qa1 = *reinterpret_cast<const bf16x8*>(&qn[qoffA + 32 + g * 8]);
    bf16x8 qb0 = *reinterpret_cast<const bf16x8*>(&qn[qoffB + g * 8]);
    bf16x8 qb1 = *reinterpret_cast<const bf16x8*>(&qn[qoffB + 32 + g * 8]);

    float lA = 0.f, lB = 0.f;
    f32x4 oA[4] = {}, oB[4] = {};

    const u16* kbase = kfrag + (((size_t)kvh * 128) << 10) + lane * 8;
    const u16* vbase = vfrag + (size_t)kvh * 64 * 2048 + lane * 8;

    // preload K for first block
    bf16x8 kf0[4], kf1[4];
#pragma unroll
    for (int sub = 0; sub < 4; ++sub) {
        const u16* kp = kbase + (size_t)((kv0 >> 4) + sub) * 1024;
        kf0[sub] = *reinterpret_cast<const bf16x8*>(kp);
        kf1[sub] = *reinterpret_cast<const bf16x8*>(kp + 512);
    }

#pragma unroll 1
    for (; kv0 < kvend; kv0 += 64) {
        // V loads first (nothing depends on them until PV -> max latency cover)
        bf16x8 vv[2][4];
#pragma unroll
        for (int sp = 0; sp < 2; ++sp)
#pragma unroll
            for (int dt = 0; dt < 4; ++dt)
                vv[sp][dt] = *reinterpret_cast<const bf16x8*>(
                    vbase + (size_t)((kv0 >> 5) + sp) * 2048 + dt * 512);

        f32x4 stA[4], stB[4];
        __builtin_amdgcn_s_setprio(1);
#pragma unroll
        for (int sub = 0; sub < 4; ++sub) {
            stA[sub] = __builtin_amdgcn_mfma_f32_16x16x32_bf16(kf0[sub], qa0, (f32x4){0.f, 0.f, 0.f, 0.f}, 0, 0, 0);
            stB[sub] = __builtin_amdgcn_mfma_f32_16x16x32_bf16(kf0[sub], qb0, (f32x4){0.f, 0.f, 0.f, 0.f}, 0, 0, 0);
            stA[sub] = __builtin_amdgcn_mfma_f32_16x16x32_bf16(kf1[sub], qa1, stA[sub], 0, 0, 0);
            stB[sub] = __builtin_amdgcn_mfma_f32_16x16x32_bf16(kf1[sub], qb1, stB[sub], 0, 0, 0);
        }
        __builtin_amdgcn_s_setprio(0);

        // K prefetch for next block (in-flight across softmax + PV)
        if (kv0 + 64 < kvend) {
#pragma unroll
            for (int sub = 0; sub < 4; ++sub) {
                const u16* kp = kbase + (size_t)(((kv0 + 64) >> 4) + sub) * 1024;
                kf0[sub] = *reinterpret_cast<const bf16x8*>(kp);
                kf1[sub] = *reinterpret_cast<const bf16x8*>(kp + 512);
            }
        }

        // causal mask; actual key via inverse permutation. A's guard also covers its
        // dead trailing block (all keys > qrowA -> fully masked -> contributes 0).
        if (kv0 + 64 > qA0) {
#pragma unroll
            for (int sub = 0; sub < 4; ++sub)
#pragma unroll
                for (int r = 0; r < 4; ++r) {
                    int key = kv0 + (sub >> 1) * 32 + g * 8 + (sub & 1) * 4 + r;
                    if (key > qrowA) stA[sub][r] = -1e30f;
                    if (key > qrowB) stB[sub][r] = -1e30f;
                }
        }

        // fixed-base softmax: weights = exp2(score'), no max tracking
        u16x8 pbA[2], pbB[2];
        float rsA = 0.f, rsB = 0.f;
#pragma unroll
        for (int sub = 0; sub < 4; ++sub)
#pragma unroll
            for (int r = 0; r < 4; ++r) {
                float eA = __builtin_amdgcn_exp2f(stA[sub][r]);
                float eB = __builtin_amdgcn_exp2f(stB[sub][r]);
                rsA += eA;
                rsB += eB;
                pbA[sub >> 1][(sub & 1) * 4 + r] = f2bf(eA);
                pbB[sub >> 1][(sub & 1) * 4 + r] = f2bf(eB);
            }
        lA += rsA;
        lB += rsB;

        __builtin_amdgcn_s_setprio(1);
#pragma unroll
        for (int sp = 0; sp < 2; ++sp) {
            bf16x8 pa = __builtin_bit_cast(bf16x8, pbA[sp]);
            bf16x8 pb = __builtin_bit_cast(bf16x8, pbB[sp]);
#pragma unroll
            for (int dt = 0; dt < 4; ++dt) {
                oA[dt] = __builtin_amdgcn_mfma_f32_16x16x32_bf16(vv[sp][dt], pa, oA[dt], 0, 0, 0);
                oB[dt] = __builtin_amdgcn_mfma_f32_16x16x32_bf16(vv[sp][dt], pb, oB[dt], 0, 0, 0);
            }
        }
        __builtin_amdgcn_s_setprio(0);
    }

    // private-slot partial writes (plain stores, no atomics); slot = (h*160+item)*2+half
    lA += __shfl_xor(lA, 16);
    lA += __shfl_xor(lA, 32);
    lB += __shfl_xor(lB, 16);
    lB += __shfl_xor(lB, 32);
    size_t slotA = ((size_t)h * 160 + item) * 2;
    if (lane < 16) {
        lbuf[slotA * 16 + cc] = lA;
        lbuf[(slotA + 1) * 16 + cc] = lB;
    }
    u16* spA = obuf + slotA * 1024;
    u16* spB = obuf + (slotA + 1) * 1024;
#pragma unroll
    for (int dt = 0; dt < 4; ++dt) {
        u16x4 ovA, ovB;
#pragma unroll
        for (int r = 0; r < 4; ++r) {
            ovA[r] = f2bf(oA[dt][r]);
            ovB[r] = f2bf(oB[dt][r]);
        }
        *reinterpret_cast<u16x4*>(&spA[cc * 64 + dt * 16 + g * 4]) = ovA;
        *reinterpret_cast<u16x4*>(&spB[cc * 64 + dt * 16 + g * 4]) = ovB;
    }
}

// ---------------- merge: attn_bf16 = sum(o_w) / (sum(l_w) + 2^(sink*log2e)) ----------------
__global__ __launch_bounds__(256) void merge_k(const u16* __restrict__ obuf,
                                               const float* __restrict__ lbuf,
                                               const float* __restrict__ sink,
                                               u16* __restrict__ attnb) {
    int row = blockIdx.x;
    int c = row >> 4, cc = row & 15;
    int t2 = c >> 1, half = c & 1;
    int nw = (t2 >> 4) + 1;  // windows for this 32-row pair
    int jb = (t2 < 16) ? t2
           : (t2 < 32) ? 16 + ((t2 - 16) << 1)
           : (t2 < 48) ? 48 + 3 * (t2 - 32)
                       : 96 + ((t2 - 48) << 2);
    int t = threadIdx.x;
    int h = t >> 3, col0 = (t & 7) * 8;

    float acc[8] = {};
    float lsum = __builtin_amdgcn_exp2f(sink[h] * LOG2E);
#pragma unroll 1
    for (int w = 0; w < nw; ++w) {
        size_t slot = ((size_t)h * 160 + jb + w) * 2 + half;
        lsum += lbuf[slot * 16 + cc];
        u16x8 v = *reinterpret_cast<const u16x8*>(&obuf[slot * 1024 + cc * 64 + col0]);
#pragma unroll
        for (int i = 0; i < 8; ++i) acc[i] += bf2f(v[i]);
    }
    float inv = 1.f / lsum;
    u16x8 ob;
#pragma unroll
    for (int i = 0; i < 8; ++i) ob[i] = f2bf(acc[i] * inv);
    *reinterpret_cast<u16x8*>(&attnb[(size_t)row * 2048 + h * 64 + col0]) = ob;
}

extern "C" void kernel_launch(void* const* d_in, const int* in_sizes, int n_in,
                              void* d_out, int out_size, void* d_ws, size_t ws_size,
                              hipStream_t stream) {
    const float* x    = (const float*)d_in[0];
    const float* cosb = (const float*)d_in[2];
    const float* sinb = (const float*)d_in[3];
    const float* wq   = (const float*)d_in[4];
    const float* wk   = (const float*)d_in[5];
    const float* wv   = (const float*)d_in[6];
    const float* wo   = (const float*)d_in[7];
    const float* qw   = (const float*)d_in[8];
    const float* kw   = (const float*)d_in[9];
    const float* sink = (const float*)d_in[10];
    float* out = (float*)d_out;

    char* ws = (char*)d_ws;
    size_t off = 0;
    auto alloc = [&](size_t bytes) {
        char* p = ws + off;
        off += (bytes + 255) & ~(size_t)255;
        return p;
    };
    u16*   xb    = (u16*)alloc((size_t)2048 * 2048 * 2);       // x bf16
    u16*   wqkvt = (u16*)alloc((size_t)3072 * 2048 * 2);       // [wq^T; wk^T; wv^T]
    u16*   wot   = (u16*)alloc((size_t)2048 * 2048 * 2);       // wo^T
    u16*   p0    = (u16*)alloc((size_t)2048 * 3072 * 2);       // GEMM1 partial z=0 (bf16)
    u16*   p1    = (u16*)alloc((size_t)2048 * 3072 * 2);       // GEMM1 partial z=1 (bf16)
    u16*   qnb   = (u16*)alloc((size_t)2048 * 2048 * 2);
    u16*   kfrag = (u16*)alloc((size_t)8 * 128 * 1024 * 2);
    u16*   vfrag = (u16*)alloc((size_t)8 * 64 * 2048 * 2);
    float* lbuf  = (float*)alloc((size_t)32 * 320 * 16 * 4);
    u16*   attnb = xb;        // xb dead after GEMM1
    u16*   obuf  = p0;        // p0+p1 (25.2 MB contiguous) dead after norm_rope/v_frag; obuf needs 21 MB
    u16*   o2p   = p0;        // obuf dead after merge_k; GEMM2 bf16 partials need 16.8 MB

    cast_bf16_k<<<2048, 256, 0, stream>>>(x, xb, 2048 * 2048 / 4);
    transpose_cast_k<<<dim3(32, 32), 256, 0, stream>>>(wq, wqkvt, 2048, 2048);
    transpose_cast_k<<<dim3(8, 32), 256, 0, stream>>>(wk, wqkvt + (size_t)2048 * 2048, 2048, 512);
    transpose_cast_k<<<dim3(8, 32), 256, 0, stream>>>(wv, wqkvt + (size_t)2560 * 2048, 2048, 512);
    transpose_cast_k<<<dim3(32, 32), 256, 0, stream>>>(wo, wot, 2048, 2048);

    gemm_bt_dbuf_k<<<dim3(24, 16, 2), 256, 0, stream>>>(xb, wqkvt, p0, 2048, 3072, 2048);
    norm_rope_k<<<20480, 256, 0, stream>>>(p0, p1, cosb, sinb, qw, kw, qnb, kfrag);
    v_frag_k<<<dim3(32, 8), 256, 0, stream>>>(p0, p1, vfrag);

    attn_k<<<dim3(8, 160), 256, 0, stream>>>(qnb, kfrag, vfrag, obuf, lbuf);
    merge_k<<<2048, 256, 0, stream>>>(obuf, lbuf, sink, attnb);

    gemm_bt_dbuf_k<<<dim3(16, 16, 2), 256, 0, stream>>>(attnb, wot, o2p, 2048, 2048, 2048);
    sum2_f32_k<<<2048, 256, 0, stream>>>(o2p, o2p + (size_t)2048 * 2048, out, 2048 * 2048 / 8);
}

// Round 10
// 153.888 us; speedup vs baseline: 1.5674x; 1.5674x over previous
//
#include <hip/hip_runtime.h>

typedef unsigned short u16;
typedef __bf16 bf16;
typedef float f32x4 __attribute__((ext_vector_type(4)));
typedef bf16 bf16x8 __attribute__((ext_vector_type(8)));
typedef short s16x4 __attribute__((ext_vector_type(4)));
typedef u16 u16x4 __attribute__((ext_vector_type(4)));
typedef u16 u16x8 __attribute__((ext_vector_type(8)));

#define SEQ 2048
#define LOG2E 1.4426950408889634f

__device__ __forceinline__ u16 f2bf(float f) {
    return __builtin_bit_cast(u16, (bf16)f);
}
__device__ __forceinline__ float bf2f(u16 u) {
    unsigned int w = ((unsigned int)u) << 16;
    return __builtin_bit_cast(float, w);
}

// ---------------- cast f32 -> bf16 (vectorized) ----------------
__global__ __launch_bounds__(256) void cast_bf16_k(const float* __restrict__ in,
                                                   u16* __restrict__ out, int n4) {
    int i = blockIdx.x * 256 + threadIdx.x;
    int stride = gridDim.x * 256;
    for (; i < n4; i += stride) {
        float4 v = reinterpret_cast<const float4*>(in)[i];
        u16x4 o;
        o[0] = f2bf(v.x); o[1] = f2bf(v.y); o[2] = f2bf(v.z); o[3] = f2bf(v.w);
        reinterpret_cast<u16x4*>(out)[i] = o;
    }
}

// ---------------- transpose + cast: src f32 [R][C] -> dst bf16 [C][R] ----------------
__global__ __launch_bounds__(256) void transpose_cast_k(const float* __restrict__ src,
                                                        u16* __restrict__ dst, int R, int C) {
    __shared__ float t[64][65];
    int c0 = blockIdx.x * 64, r0 = blockIdx.y * 64;
    int tx = threadIdx.x & 63, ty = threadIdx.x >> 6;
#pragma unroll
    for (int i = 0; i < 16; ++i) {
        int r = ty + i * 4;
        t[r][tx] = src[(size_t)(r0 + r) * C + c0 + tx];
    }
    __syncthreads();
#pragma unroll
    for (int i = 0; i < 16; ++i) {
        int c = ty + i * 4;
        dst[(size_t)(c0 + c) * R + r0 + tx] = f2bf(t[tx][c]);
    }
}

// ---------------- GEMM partial: Cp[z][M,N](bf16) = A[M,kz] @ Bt[N,kz]^T ----------------
// 128x128 tile, BK=32, split-K (blockIdx.z), double-buffered LDS with prefetch,
// XOR-swizzled LDS slots (pre-swizzled gload_lds source + swizzled ds_read; rule #21).
__global__ __launch_bounds__(256) void gemm_bt_dbuf_k(const u16* __restrict__ A,
                                                      const u16* __restrict__ Bt,
                                                      u16* __restrict__ Cp,
                                                      int M, int N, int K) {
    __shared__ __align__(16) u16 As[2][128 * 32];
    __shared__ __align__(16) u16 Bs[2][128 * 32];
    int tid = threadIdx.x;
    int wave = tid >> 6, lane = tid & 63;
    int bm = blockIdx.y * 128, bn = blockIdx.x * 128;
    int z = blockIdx.z;
    int kt0 = z * (K >> 1), ktend = kt0 + (K >> 1);
    int wm = (wave >> 1) * 64, wn = (wave & 1) * 64;
    int g = lane >> 4, cidx = lane & 15;
    f32x4 acc[4][4] = {};

    // staging: LDS slot (srow, lane&3) holds global k-chunk (lane&3) ^ ((srow>>1)&3)
    int srow = lane >> 2;
    int skol = ((lane & 3) ^ ((srow >> 1) & 3)) * 8;
    // read: logical chunk g of row r lives at slot g ^ ((r_in16>>1)&3); r_in16 = cidx
    int sl8 = (g ^ ((cidx >> 1) & 3)) * 8;

#define STAGE(buf, kt)                                                                \
    {                                                                                 \
        _Pragma("unroll")                                                             \
        for (int j = 0; j < 2; ++j) {                                                 \
            const u16* gpa = A + (size_t)(bm + (wave * 2 + j) * 16 + srow) * K + (kt) + skol; \
            __builtin_amdgcn_global_load_lds(                                         \
                (__attribute__((address_space(1))) void*)gpa,                         \
                (__attribute__((address_space(3))) void*)&As[buf][(wave * 2 + j) * 512], \
                16, 0, 0);                                                            \
        }                                                                             \
        _Pragma("unroll")                                                             \
        for (int j = 0; j < 2; ++j) {                                                 \
            const u16* gpb = Bt + (size_t)(bn + (wave * 2 + j) * 16 + srow) * K + (kt) + skol; \
            __builtin_amdgcn_global_load_lds(                                         \
                (__attribute__((address_space(1))) void*)gpb,                         \
                (__attribute__((address_space(3))) void*)&Bs[buf][(wave * 2 + j) * 512], \
                16, 0, 0);                                                            \
        }                                                                             \
    }

    STAGE(0, kt0);
    asm volatile("s_waitcnt vmcnt(0)" ::: "memory");
    __syncthreads();

    int cur = 0;
#pragma unroll 1
    for (int kt = kt0; kt < ktend; kt += 32) {
        if (kt + 32 < ktend) STAGE(cur ^ 1, kt + 32);  // prefetch in flight across compute

        bf16x8 af[4], bfr[4];
#pragma unroll
        for (int mi = 0; mi < 4; ++mi)
            af[mi] = *reinterpret_cast<const bf16x8*>(&As[cur][(wm + mi * 16 + cidx) * 32 + sl8]);
#pragma unroll
        for (int ni = 0; ni < 4; ++ni)
            bfr[ni] = *reinterpret_cast<const bf16x8*>(&Bs[cur][(wn + ni * 16 + cidx) * 32 + sl8]);
#pragma unroll
        for (int mi = 0; mi < 4; ++mi)
#pragma unroll
            for (int ni = 0; ni < 4; ++ni)
                acc[mi][ni] = __builtin_amdgcn_mfma_f32_16x16x32_bf16(af[mi], bfr[ni], acc[mi][ni], 0, 0, 0);

        asm volatile("s_waitcnt vmcnt(0)" ::: "memory");
        __syncthreads();
        cur ^= 1;
    }
#undef STAGE

    u16* cbase = Cp + (size_t)z * M * N;
#pragma unroll
    for (int mi = 0; mi < 4; ++mi) {
#pragma unroll
        for (int r = 0; r < 4; ++r) {
            int row = bm + wm + mi * 16 + g * 4 + r;
            u16* cp = cbase + (size_t)row * N + bn + wn + cidx;
#pragma unroll
            for (int ni = 0; ni < 4; ++ni)
                cp[ni * 16] = f2bf(acc[mi][ni][r]);
        }
    }
}

// ---------------- sum two bf16 partials -> f32 ----------------
__global__ __launch_bounds__(256) void sum2_f32_k(const u16* __restrict__ a,
                                                  const u16* __restrict__ b,
                                                  float* __restrict__ out, int n8) {
    int i = blockIdx.x * 256 + threadIdx.x;
    if (i >= n8) return;
    u16x8 va = reinterpret_cast<const u16x8*>(a)[i];
    u16x8 vb = reinterpret_cast<const u16x8*>(b)[i];
    f32x4 lo, hi;
#pragma unroll
    for (int j = 0; j < 4; ++j) {
        lo[j] = bf2f(va[j]) + bf2f(vb[j]);
        hi[j] = bf2f(va[4 + j]) + bf2f(vb[4 + j]);
    }
    reinterpret_cast<f32x4*>(out)[i * 2] = lo;
    reinterpret_cast<f32x4*>(out)[i * 2 + 1] = hi;
}

// ---------------- RMSNorm + RoPE for Q and K heads (sums split-K partials) ----------------
// Q: pre-scaled by 0.125*log2(e) (exp2-base softmax), row-major [s][32*64]
// K: MFMA A-fragment order with PERMUTED key placement inside each 32-key group:
//   k32 -> phys (sub = bit2, row = (k32>>3)*4 + (k32&3)); this makes two QK 16-subs
//   concatenate into a K=32 PV B-fragment (lane g holds keys g*8..g*8+7).
__global__ __launch_bounds__(256) void norm_rope_k(const u16* __restrict__ p0,
                                                   const u16* __restrict__ p1,
                                                   const float* __restrict__ cosb,
                                                   const float* __restrict__ sinb,
                                                   const float* __restrict__ qw,
                                                   const float* __restrict__ kw,
                                                   u16* __restrict__ qn,
                                                   u16* __restrict__ kfrag) {
    int idx = blockIdx.x * 4 + (threadIdx.x >> 6);
    int lane = threadIdx.x & 63;
    int s = idx / 40, hh = idx - s * 40;
    size_t off = (hh < 32) ? ((size_t)s * 3072 + hh * 64 + lane)
                           : ((size_t)s * 3072 + 2048 + (hh - 32) * 64 + lane);
    float val = bf2f(p0[off]) + bf2f(p1[off]);
    float ss = val * val;
#pragma unroll
    for (int mm = 32; mm; mm >>= 1) ss += __shfl_xor(ss, mm);
    float w = (hh < 32) ? qw[lane] : kw[lane];
    float xn = val * rsqrtf(ss * (1.f / 64.f) + 1e-6f) * w;
    float part = __shfl_xor(xn, 32);
    float rot = (lane < 32) ? -part : part;
    float o = xn * cosb[s * 64 + lane] + rot * sinb[s * 64 + lane];
    if (hh < 32) {
        qn[(size_t)s * 2048 + hh * 64 + lane] = f2bf(o * (0.125f * LOG2E));
    } else {
        int h8 = hh - 32;
        int k32 = s & 31;
        int p32 = ((k32 >> 2) & 1) * 16 + ((k32 >> 3) << 2) + (k32 & 3);
        int p = (s & ~31) + p32;
        kfrag[(((size_t)h8 * 128 + (p >> 4)) << 10) + (lane >> 3) * 128 + (p & 15) * 8 + (lane & 7)] = f2bf(o);
    }
}

// ---------------- V in K=32 PV A-fragment order ----------------
// vfrag[kvh][kb32][dt][lane(g*16+cc)][i] = V[kb32*32 + g*8 + i][dt*16 + cc]
__global__ __launch_bounds__(256) void v_frag_k(const u16* __restrict__ p0,
                                                const u16* __restrict__ p1,
                                                u16* __restrict__ vfrag) {
    __shared__ float t[64][65];
    int s0 = blockIdx.x * 64;
    int h = blockIdx.y;
    int tx = threadIdx.x & 63, ty = threadIdx.x >> 6;
#pragma unroll
    for (int i = 0; i < 16; ++i) {
        int r = ty + i * 4;
        size_t off = (size_t)(s0 + r) * 3072 + 2560 + h * 64 + tx;
        t[r][tx] = bf2f(p0[off]) + bf2f(p1[off]);
    }
    __syncthreads();
    int dt = threadIdx.x >> 6, g = (threadIdx.x >> 4) & 3, cc = threadIdx.x & 15;
#pragma unroll
    for (int kb = 0; kb < 2; ++kb) {
        u16x8 o;
#pragma unroll
        for (int i = 0; i < 8; ++i) o[i] = f2bf(t[kb * 32 + g * 8 + i][dt * 16 + cc]);
        *reinterpret_cast<u16x8*>(
            &vfrag[((size_t)h * 64 + (s0 >> 5) + kb) * 2048 + dt * 512 + (size_t)(threadIdx.x & 63) * 8]) = o;
    }
}

// ---------------- Flash attention: full-range waves, direct final output ----------------
// block = (kvh, chunk c = 127 - blockIdx.y); 4 waves = 4 q-heads of the GQA group
// (shared K/V address stream -> one L2/L1 fetch serves 4 waves; identical trip counts
// so the lockstep s_barrier is legal). Each wave walks its chunk's FULL key range
// (1..32 iterations, long chunks dispatched first), completes l in-wave, folds the
// sink term, and writes FINAL bf16 attn directly (8 MB coalesced) — no partial slots,
// no lbuf/obuf traffic, no merge kernel (R6-R8 were bound by that partial traffic at
// ~550 GB/s effective).
// NOTE: launch_bounds min-waves MUST stay <=4: (256,8) capped VGPR at 32 and spilled
// ~1.3 GB of scratch (R4); dual-stream state also spills at 128 VGPR (R9 regression).
__global__ __launch_bounds__(256, 4) void attn_k(const u16* __restrict__ qn,
                                                 const u16* __restrict__ kfrag,
                                                 const u16* __restrict__ vfrag,
                                                 const float* __restrict__ sink,
                                                 u16* __restrict__ attnb) {
    int kvh = blockIdx.x;
    int wave = threadIdx.x >> 6, lane = threadIdx.x & 63;
    int h = kvh * 4 + wave;
    int c = 127 - blockIdx.y;   // reversed: longest chunks dispatch first
    int q0 = c * 16;
    int kvend = q0 + 16;

    int g = lane >> 4, cc = lane & 15;
    int qrow = q0 + cc;

    const size_t qoff = (size_t)qrow * 2048 + h * 64;
    bf16x8 q_0 = *reinterpret_cast<const bf16x8*>(&qn[qoff + g * 8]);
    bf16x8 q_1 = *reinterpret_cast<const bf16x8*>(&qn[qoff + 32 + g * 8]);

    float l = 0.f;
    f32x4 o[4] = {};

    const u16* kbase = kfrag + (((size_t)kvh * 128) << 10) + lane * 8;
    const u16* vbase = vfrag + (size_t)kvh * 64 * 2048 + lane * 8;

    // preload K for first block
    bf16x8 kf0[4], kf1[4];
#pragma unroll
    for (int sub = 0; sub < 4; ++sub) {
        const u16* kp = kbase + (size_t)sub * 1024;
        kf0[sub] = *reinterpret_cast<const bf16x8*>(kp);
        kf1[sub] = *reinterpret_cast<const bf16x8*>(kp + 512);
    }

#pragma unroll 1
    for (int kv0 = 0; kv0 < kvend; kv0 += 64) {
        __builtin_amdgcn_s_barrier();  // lockstep hint: keeps 4 waves' shared K/V reads coincident

        // V loads first (nothing depends on them until PV -> max latency cover)
        bf16x8 vv[2][4];
#pragma unroll
        for (int sp = 0; sp < 2; ++sp)
#pragma unroll
            for (int dt = 0; dt < 4; ++dt)
                vv[sp][dt] = *reinterpret_cast<const bf16x8*>(
                    vbase + (size_t)((kv0 >> 5) + sp) * 2048 + dt * 512);

        f32x4 st[4];
        __builtin_amdgcn_s_setprio(1);
#pragma unroll
        for (int sub = 0; sub < 4; ++sub) {
            st[sub] = __builtin_amdgcn_mfma_f32_16x16x32_bf16(kf0[sub], q_0, (f32x4){0.f, 0.f, 0.f, 0.f}, 0, 0, 0);
            st[sub] = __builtin_amdgcn_mfma_f32_16x16x32_bf16(kf1[sub], q_1, st[sub], 0, 0, 0);
        }
        __builtin_amdgcn_s_setprio(0);

        // K prefetch for next block (in-flight across softmax + PV)
        if (kv0 + 64 < kvend) {
#pragma unroll
            for (int sub = 0; sub < 4; ++sub) {
                const u16* kp = kbase + (size_t)(((kv0 + 64) >> 4) + sub) * 1024;
                kf0[sub] = *reinterpret_cast<const bf16x8*>(kp);
                kf1[sub] = *reinterpret_cast<const bf16x8*>(kp + 512);
            }
        }

        // causal mask (diagonal block only); actual key via inverse permutation
        if (kv0 + 64 > q0) {
#pragma unroll
            for (int sub = 0; sub < 4; ++sub)
#pragma unroll
                for (int r = 0; r < 4; ++r) {
                    int key = kv0 + (sub >> 1) * 32 + g * 8 + (sub & 1) * 4 + r;
                    if (key > qrow) st[sub][r] = -1e30f;
                }
        }

        // fixed-base softmax: weights = exp2(score'), no max tracking
        u16x8 pb[2];
        float rs = 0.f;
#pragma unroll
        for (int sub = 0; sub < 4; ++sub)
#pragma unroll
            for (int r = 0; r < 4; ++r) {
                float e = __builtin_amdgcn_exp2f(st[sub][r]);
                rs += e;
                pb[sub >> 1][(sub & 1) * 4 + r] = f2bf(e);
            }
        l += rs;

        __builtin_amdgcn_s_setprio(1);
#pragma unroll
        for (int sp = 0; sp < 2; ++sp) {
            bf16x8 pbb = __builtin_bit_cast(bf16x8, pb[sp]);
#pragma unroll
            for (int dt = 0; dt < 4; ++dt)
                o[dt] = __builtin_amdgcn_mfma_f32_16x16x32_bf16(vv[sp][dt], pbb, o[dt], 0, 0, 0);
        }
        __builtin_amdgcn_s_setprio(0);
    }

    // complete softmax: fold sink into denominator, write FINAL attn (coalesced)
    l += __shfl_xor(l, 16);
    l += __shfl_xor(l, 32);
    float inv = 1.f / (l + __builtin_amdgcn_exp2f(sink[h] * LOG2E));
#pragma unroll
    for (int dt = 0; dt < 4; ++dt) {
        u16x4 ov;
#pragma unroll
        for (int r = 0; r < 4; ++r) ov[r] = f2bf(o[dt][r] * inv);
        *reinterpret_cast<u16x4*>(&attnb[(size_t)qrow * 2048 + h * 64 + dt * 16 + g * 4]) = ov;
    }
}

extern "C" void kernel_launch(void* const* d_in, const int* in_sizes, int n_in,
                              void* d_out, int out_size, void* d_ws, size_t ws_size,
                              hipStream_t stream) {
    const float* x    = (const float*)d_in[0];
    const float* cosb = (const float*)d_in[2];
    const float* sinb = (const float*)d_in[3];
    const float* wq   = (const float*)d_in[4];
    const float* wk   = (const float*)d_in[5];
    const float* wv   = (const float*)d_in[6];
    const float* wo   = (const float*)d_in[7];
    const float* qw   = (const float*)d_in[8];
    const float* kw   = (const float*)d_in[9];
    const float* sink = (const float*)d_in[10];
    float* out = (float*)d_out;

    char* ws = (char*)d_ws;
    size_t off = 0;
    auto alloc = [&](size_t bytes) {
        char* p = ws + off;
        off += (bytes + 255) & ~(size_t)255;
        return p;
    };
    u16*   xb    = (u16*)alloc((size_t)2048 * 2048 * 2);       // x bf16
    u16*   wqkvt = (u16*)alloc((size_t)3072 * 2048 * 2);       // [wq^T; wk^T; wv^T]
    u16*   wot   = (u16*)alloc((size_t)2048 * 2048 * 2);       // wo^T
    u16*   p0    = (u16*)alloc((size_t)2048 * 3072 * 2);       // GEMM1 partial z=0 (bf16)
    u16*   p1    = (u16*)alloc((size_t)2048 * 3072 * 2);       // GEMM1 partial z=1 (bf16)
    u16*   qnb   = (u16*)alloc((size_t)2048 * 2048 * 2);
    u16*   kfrag = (u16*)alloc((size_t)8 * 128 * 1024 * 2);
    u16*   vfrag = (u16*)alloc((size_t)8 * 64 * 2048 * 2);
    u16*   attnb = xb;        // xb dead after GEMM1
    u16*   o2p   = p0;        // p0/p1 dead after norm_rope/v_frag; GEMM2 bf16 partials need 16.8 MB

    cast_bf16_k<<<2048, 256, 0, stream>>>(x, xb, 2048 * 2048 / 4);
    transpose_cast_k<<<dim3(32, 32), 256, 0, stream>>>(wq, wqkvt, 2048, 2048);
    transpose_cast_k<<<dim3(8, 32), 256, 0, stream>>>(wk, wqkvt + (size_t)2048 * 2048, 2048, 512);
    transpose_cast_k<<<dim3(8, 32), 256, 0, stream>>>(wv, wqkvt + (size_t)2560 * 2048, 2048, 512);
    transpose_cast_k<<<dim3(32, 32), 256, 0, stream>>>(wo, wot, 2048, 2048);

    gemm_bt_dbuf_k<<<dim3(24, 16, 2), 256, 0, stream>>>(xb, wqkvt, p0, 2048, 3072, 2048);
    norm_rope_k<<<20480, 256, 0, stream>>>(p0, p1, cosb, sinb, qw, kw, qnb, kfrag);
    v_frag_k<<<dim3(32, 8), 256, 0, stream>>>(p0, p1, vfrag);

    attn_k<<<dim3(8, 128), 256, 0, stream>>>(qnb, kfrag, vfrag, sink, attnb);

    gemm_bt_dbuf_k<<<dim3(16, 16, 2), 256, 0, stream>>>(attnb, wot, o2p, 2048, 2048, 2048);
    sum2_f32_k<<<2048, 256, 0, stream>>>(o2p, o2p + (size_t)2048 * 2048, out, 2048 * 2048 / 8);
}

// Round 11
// 149.419 us; speedup vs baseline: 1.6143x; 1.0299x over previous
//
#include <hip/hip_runtime.h>

typedef unsigned short u16;
typedef __bf16 bf16;
typedef float f32x4 __attribute__((ext_vector_type(4)));
typedef bf16 bf16x8 __attribute__((ext_vector_type(8)));
typedef short s16x4 __attribute__((ext_vector_type(4)));
typedef u16 u16x4 __attribute__((ext_vector_type(4)));
typedef u16 u16x8 __attribute__((ext_vector_type(8)));

#define SEQ 2048
#define LOG2E 1.4426950408889634f

__device__ __forceinline__ u16 f2bf(float f) {
    return __builtin_bit_cast(u16, (bf16)f);
}
__device__ __forceinline__ float bf2f(u16 u) {
    unsigned int w = ((unsigned int)u) << 16;
    return __builtin_bit_cast(float, w);
}

// ---------------- cast f32 -> bf16 (vectorized) ----------------
__global__ __launch_bounds__(256) void cast_bf16_k(const float* __restrict__ in,
                                                   u16* __restrict__ out, int n4) {
    int i = blockIdx.x * 256 + threadIdx.x;
    int stride = gridDim.x * 256;
    for (; i < n4; i += stride) {
        float4 v = reinterpret_cast<const float4*>(in)[i];
        u16x4 o;
        o[0] = f2bf(v.x); o[1] = f2bf(v.y); o[2] = f2bf(v.z); o[3] = f2bf(v.w);
        reinterpret_cast<u16x4*>(out)[i] = o;
    }
}

// ---------------- transpose + cast: src f32 [R][C] -> dst bf16 [C][R] ----------------
__global__ __launch_bounds__(256) void transpose_cast_k(const float* __restrict__ src,
                                                        u16* __restrict__ dst, int R, int C) {
    __shared__ float t[64][65];
    int c0 = blockIdx.x * 64, r0 = blockIdx.y * 64;
    int tx = threadIdx.x & 63, ty = threadIdx.x >> 6;
#pragma unroll
    for (int i = 0; i < 16; ++i) {
        int r = ty + i * 4;
        t[r][tx] = src[(size_t)(r0 + r) * C + c0 + tx];
    }
    __syncthreads();
#pragma unroll
    for (int i = 0; i < 16; ++i) {
        int c = ty + i * 4;
        dst[(size_t)(c0 + c) * R + r0 + tx] = f2bf(t[tx][c]);
    }
}

// ---------------- GEMM partial: Cp[z][M,N](bf16) = A[M,kz] @ Bt[N,kz]^T ----------------
// 128x128 tile, BK=32, split-K (blockIdx.z), double-buffered LDS with prefetch,
// XOR-swizzled LDS slots (pre-swizzled gload_lds source + swizzled ds_read; rule #21).
__global__ __launch_bounds__(256) void gemm_bt_dbuf_k(const u16* __restrict__ A,
                                                      const u16* __restrict__ Bt,
                                                      u16* __restrict__ Cp,
                                                      int M, int N, int K) {
    __shared__ __align__(16) u16 As[2][128 * 32];
    __shared__ __align__(16) u16 Bs[2][128 * 32];
    int tid = threadIdx.x;
    int wave = tid >> 6, lane = tid & 63;
    int bm = blockIdx.y * 128, bn = blockIdx.x * 128;
    int z = blockIdx.z;
    int kt0 = z * (K >> 1), ktend = kt0 + (K >> 1);
    int wm = (wave >> 1) * 64, wn = (wave & 1) * 64;
    int g = lane >> 4, cidx = lane & 15;
    f32x4 acc[4][4] = {};

    // staging: LDS slot (srow, lane&3) holds global k-chunk (lane&3) ^ ((srow>>1)&3)
    int srow = lane >> 2;
    int skol = ((lane & 3) ^ ((srow >> 1) & 3)) * 8;
    // read: logical chunk g of row r lives at slot g ^ ((r_in16>>1)&3); r_in16 = cidx
    int sl8 = (g ^ ((cidx >> 1) & 3)) * 8;

#define STAGE(buf, kt)                                                                \
    {                                                                                 \
        _Pragma("unroll")                                                             \
        for (int j = 0; j < 2; ++j) {                                                 \
            const u16* gpa = A + (size_t)(bm + (wave * 2 + j) * 16 + srow) * K + (kt) + skol; \
            __builtin_amdgcn_global_load_lds(                                         \
                (__attribute__((address_space(1))) void*)gpa,                         \
                (__attribute__((address_space(3))) void*)&As[buf][(wave * 2 + j) * 512], \
                16, 0, 0);                                                            \
        }                                                                             \
        _Pragma("unroll")                                                             \
        for (int j = 0; j < 2; ++j) {                                                 \
            const u16* gpb = Bt + (size_t)(bn + (wave * 2 + j) * 16 + srow) * K + (kt) + skol; \
            __builtin_amdgcn_global_load_lds(                                         \
                (__attribute__((address_space(1))) void*)gpb,                         \
                (__attribute__((address_space(3))) void*)&Bs[buf][(wave * 2 + j) * 512], \
                16, 0, 0);                                                            \
        }                                                                             \
    }

    STAGE(0, kt0);
    asm volatile("s_waitcnt vmcnt(0)" ::: "memory");
    __syncthreads();

    int cur = 0;
#pragma unroll 1
    for (int kt = kt0; kt < ktend; kt += 32) {
        if (kt + 32 < ktend) STAGE(cur ^ 1, kt + 32);  // prefetch in flight across compute

        bf16x8 af[4], bfr[4];
#pragma unroll
        for (int mi = 0; mi < 4; ++mi)
            af[mi] = *reinterpret_cast<const bf16x8*>(&As[cur][(wm + mi * 16 + cidx) * 32 + sl8]);
#pragma unroll
        for (int ni = 0; ni < 4; ++ni)
            bfr[ni] = *reinterpret_cast<const bf16x8*>(&Bs[cur][(wn + ni * 16 + cidx) * 32 + sl8]);
#pragma unroll
        for (int mi = 0; mi < 4; ++mi)
#pragma unroll
            for (int ni = 0; ni < 4; ++ni)
                acc[mi][ni] = __builtin_amdgcn_mfma_f32_16x16x32_bf16(af[mi], bfr[ni], acc[mi][ni], 0, 0, 0);

        asm volatile("s_waitcnt vmcnt(0)" ::: "memory");
        __syncthreads();
        cur ^= 1;
    }
#undef STAGE

    u16* cbase = Cp + (size_t)z * M * N;
#pragma unroll
    for (int mi = 0; mi < 4; ++mi) {
#pragma unroll
        for (int r = 0; r < 4; ++r) {
            int row = bm + wm + mi * 16 + g * 4 + r;
            u16* cp = cbase + (size_t)row * N + bn + wn + cidx;
#pragma unroll
            for (int ni = 0; ni < 4; ++ni)
                cp[ni * 16] = f2bf(acc[mi][ni][r]);
        }
    }
}

// ---------------- sum two bf16 partials -> f32 ----------------
__global__ __launch_bounds__(256) void sum2_f32_k(const u16* __restrict__ a,
                                                  const u16* __restrict__ b,
                                                  float* __restrict__ out, int n8) {
    int i = blockIdx.x * 256 + threadIdx.x;
    if (i >= n8) return;
    u16x8 va = reinterpret_cast<const u16x8*>(a)[i];
    u16x8 vb = reinterpret_cast<const u16x8*>(b)[i];
    f32x4 lo, hi;
#pragma unroll
    for (int j = 0; j < 4; ++j) {
        lo[j] = bf2f(va[j]) + bf2f(vb[j]);
        hi[j] = bf2f(va[4 + j]) + bf2f(vb[4 + j]);
    }
    reinterpret_cast<f32x4*>(out)[i * 2] = lo;
    reinterpret_cast<f32x4*>(out)[i * 2 + 1] = hi;
}

// ---------------- RMSNorm + RoPE for Q and K heads (sums split-K partials) ----------------
// Q: pre-scaled by 0.125*log2(e) (exp2-base softmax), row-major [s][32*64]
// K: MFMA A-fragment order with PERMUTED key placement inside each 32-key group:
//   k32 -> phys (sub = bit2, row = (k32>>3)*4 + (k32&3)); this makes two QK 16-subs
//   concatenate into a K=32 PV B-fragment (lane g holds keys g*8..g*8+7).
__global__ __launch_bounds__(256) void norm_rope_k(const u16* __restrict__ p0,
                                                   const u16* __restrict__ p1,
                                                   const float* __restrict__ cosb,
                                                   const float* __restrict__ sinb,
                                                   const float* __restrict__ qw,
                                                   const float* __restrict__ kw,
                                                   u16* __restrict__ qn,
                                                   u16* __restrict__ kfrag) {
    int idx = blockIdx.x * 4 + (threadIdx.x >> 6);
    int lane = threadIdx.x & 63;
    int s = idx / 40, hh = idx - s * 40;
    size_t off = (hh < 32) ? ((size_t)s * 3072 + hh * 64 + lane)
                           : ((size_t)s * 3072 + 2048 + (hh - 32) * 64 + lane);
    float val = bf2f(p0[off]) + bf2f(p1[off]);
    float ss = val * val;
#pragma unroll
    for (int mm = 32; mm; mm >>= 1) ss += __shfl_xor(ss, mm);
    float w = (hh < 32) ? qw[lane] : kw[lane];
    float xn = val * rsqrtf(ss * (1.f / 64.f) + 1e-6f) * w;
    float part = __shfl_xor(xn, 32);
    float rot = (lane < 32) ? -part : part;
    float o = xn * cosb[s * 64 + lane] + rot * sinb[s * 64 + lane];
    if (hh < 32) {
        qn[(size_t)s * 2048 + hh * 64 + lane] = f2bf(o * (0.125f * LOG2E));
    } else {
        int h8 = hh - 32;
        int k32 = s & 31;
        int p32 = ((k32 >> 2) & 1) * 16 + ((k32 >> 3) << 2) + (k32 & 3);
        int p = (s & ~31) + p32;
        kfrag[(((size_t)h8 * 128 + (p >> 4)) << 10) + (lane >> 3) * 128 + (p & 15) * 8 + (lane & 7)] = f2bf(o);
    }
}

// ---------------- V in K=32 PV A-fragment order ----------------
// vfrag[kvh][kb32][dt][lane(g*16+cc)][i] = V[kb32*32 + g*8 + i][dt*16 + cc]
__global__ __launch_bounds__(256) void v_frag_k(const u16* __restrict__ p0,
                                                const u16* __restrict__ p1,
                                                u16* __restrict__ vfrag) {
    __shared__ float t[64][65];
    int s0 = blockIdx.x * 64;
    int h = blockIdx.y;
    int tx = threadIdx.x & 63, ty = threadIdx.x >> 6;
#pragma unroll
    for (int i = 0; i < 16; ++i) {
        int r = ty + i * 4;
        size_t off = (size_t)(s0 + r) * 3072 + 2560 + h * 64 + tx;
        t[r][tx] = bf2f(p0[off]) + bf2f(p1[off]);
    }
    __syncthreads();
    int dt = threadIdx.x >> 6, g = (threadIdx.x >> 4) & 3, cc = threadIdx.x & 15;
#pragma unroll
    for (int kb = 0; kb < 2; ++kb) {
        u16x8 o;
#pragma unroll
        for (int i = 0; i < 8; ++i) o[i] = f2bf(t[kb * 32 + g * 8 + i][dt * 16 + cc]);
        *reinterpret_cast<u16x8*>(
            &vfrag[((size_t)h * 64 + (s0 >> 5) + kb) * 2048 + dt * 512 + (size_t)(threadIdx.x & 63) * 8]) = o;
    }
}

// ---------------- Flash attention: SINGLE-WAVE blocks, full-range, direct output ----------------
// grid (32 heads, 128 chunks), block = 64 threads = 1 wave, no barrier. 4096 blocks ->
// 16 blocks/CU resident = 4 independent waves/SIMD at DIFFERENT phases (R8/R10's 4-wave
// lockstep blocks gave only ~2.3 phase-identical waves/SIMD — latency never overlapped).
// Each wave walks its chunk's full key range (long chunks dispatched first), completes l,
// folds the sink term, writes final bf16 attn coalesced. K/V fully L2-resident (FETCH 6MB).
// NOTE: VGPR cap must stay >=128: (256,8) spilled 1.3 GB scratch (R4); dual-stream
// register state also spilled (R9).
__global__ __launch_bounds__(64, 4) void attn_k(const u16* __restrict__ qn,
                                                const u16* __restrict__ kfrag,
                                                const u16* __restrict__ vfrag,
                                                const float* __restrict__ sink,
                                                u16* __restrict__ attnb) {
    int h = blockIdx.x;
    int kvh = h >> 2;
    int c = 127 - blockIdx.y;   // reversed: longest chunks dispatch first
    int q0 = c * 16;
    int kvend = q0 + 16;
    int lane = threadIdx.x;

    int g = lane >> 4, cc = lane & 15;
    int qrow = q0 + cc;

    const size_t qoff = (size_t)qrow * 2048 + h * 64;
    bf16x8 q_0 = *reinterpret_cast<const bf16x8*>(&qn[qoff + g * 8]);
    bf16x8 q_1 = *reinterpret_cast<const bf16x8*>(&qn[qoff + 32 + g * 8]);

    float l = 0.f;
    f32x4 o[4] = {};

    const u16* kbase = kfrag + (((size_t)kvh * 128) << 10) + lane * 8;
    const u16* vbase = vfrag + (size_t)kvh * 64 * 2048 + lane * 8;

    // preload K for first block
    bf16x8 kf0[4], kf1[4];
#pragma unroll
    for (int sub = 0; sub < 4; ++sub) {
        const u16* kp = kbase + (size_t)sub * 1024;
        kf0[sub] = *reinterpret_cast<const bf16x8*>(kp);
        kf1[sub] = *reinterpret_cast<const bf16x8*>(kp + 512);
    }

#pragma unroll 1
    for (int kv0 = 0; kv0 < kvend; kv0 += 64) {
        // V loads first (nothing depends on them until PV -> max latency cover)
        bf16x8 vv[2][4];
#pragma unroll
        for (int sp = 0; sp < 2; ++sp)
#pragma unroll
            for (int dt = 0; dt < 4; ++dt)
                vv[sp][dt] = *reinterpret_cast<const bf16x8*>(
                    vbase + (size_t)((kv0 >> 5) + sp) * 2048 + dt * 512);

        f32x4 st[4];
        __builtin_amdgcn_s_setprio(1);
#pragma unroll
        for (int sub = 0; sub < 4; ++sub) {
            st[sub] = __builtin_amdgcn_mfma_f32_16x16x32_bf16(kf0[sub], q_0, (f32x4){0.f, 0.f, 0.f, 0.f}, 0, 0, 0);
            st[sub] = __builtin_amdgcn_mfma_f32_16x16x32_bf16(kf1[sub], q_1, st[sub], 0, 0, 0);
        }
        __builtin_amdgcn_s_setprio(0);

        // K prefetch for next block (in-flight across softmax + PV)
        if (kv0 + 64 < kvend) {
#pragma unroll
            for (int sub = 0; sub < 4; ++sub) {
                const u16* kp = kbase + (size_t)(((kv0 + 64) >> 4) + sub) * 1024;
                kf0[sub] = *reinterpret_cast<const bf16x8*>(kp);
                kf1[sub] = *reinterpret_cast<const bf16x8*>(kp + 512);
            }
        }

        // causal mask (diagonal block only); actual key via inverse permutation
        if (kv0 + 64 > q0) {
#pragma unroll
            for (int sub = 0; sub < 4; ++sub)
#pragma unroll
                for (int r = 0; r < 4; ++r) {
                    int key = kv0 + (sub >> 1) * 32 + g * 8 + (sub & 1) * 4 + r;
                    if (key > qrow) st[sub][r] = -1e30f;
                }
        }

        // fixed-base softmax: weights = exp2(score'), no max tracking
        u16x8 pb[2];
        float rs = 0.f;
#pragma unroll
        for (int sub = 0; sub < 4; ++sub)
#pragma unroll
            for (int r = 0; r < 4; ++r) {
                float e = __builtin_amdgcn_exp2f(st[sub][r]);
                rs += e;
                pb[sub >> 1][(sub & 1) * 4 + r] = f2bf(e);
            }
        l += rs;

        __builtin_amdgcn_s_setprio(1);
#pragma unroll
        for (int sp = 0; sp < 2; ++sp) {
            bf16x8 pbb = __builtin_bit_cast(bf16x8, pb[sp]);
#pragma unroll
            for (int dt = 0; dt < 4; ++dt)
                o[dt] = __builtin_amdgcn_mfma_f32_16x16x32_bf16(vv[sp][dt], pbb, o[dt], 0, 0, 0);
        }
        __builtin_amdgcn_s_setprio(0);
    }

    // complete softmax: fold sink into denominator, write FINAL attn (coalesced)
    l += __shfl_xor(l, 16);
    l += __shfl_xor(l, 32);
    float inv = 1.f / (l + __builtin_amdgcn_exp2f(sink[h] * LOG2E));
#pragma unroll
    for (int dt = 0; dt < 4; ++dt) {
        u16x4 ov;
#pragma unroll
        for (int r = 0; r < 4; ++r) ov[r] = f2bf(o[dt][r] * inv);
        *reinterpret_cast<u16x4*>(&attnb[(size_t)qrow * 2048 + h * 64 + dt * 16 + g * 4]) = ov;
    }
}

extern "C" void kernel_launch(void* const* d_in, const int* in_sizes, int n_in,
                              void* d_out, int out_size, void* d_ws, size_t ws_size,
                              hipStream_t stream) {
    const float* x    = (const float*)d_in[0];
    const float* cosb = (const float*)d_in[2];
    const float* sinb = (const float*)d_in[3];
    const float* wq   = (const float*)d_in[4];
    const float* wk   = (const float*)d_in[5];
    const float* wv   = (const float*)d_in[6];
    const float* wo   = (const float*)d_in[7];
    const float* qw   = (const float*)d_in[8];
    const float* kw   = (const float*)d_in[9];
    const float* sink = (const float*)d_in[10];
    float* out = (float*)d_out;

    char* ws = (char*)d_ws;
    size_t off = 0;
    auto alloc = [&](size_t bytes) {
        char* p = ws + off;
        off += (bytes + 255) & ~(size_t)255;
        return p;
    };
    u16*   xb    = (u16*)alloc((size_t)2048 * 2048 * 2);       // x bf16
    u16*   wqkvt = (u16*)alloc((size_t)3072 * 2048 * 2);       // [wq^T; wk^T; wv^T]
    u16*   wot   = (u16*)alloc((size_t)2048 * 2048 * 2);       // wo^T
    u16*   p0    = (u16*)alloc((size_t)2048 * 3072 * 2);       // GEMM1 partial z=0 (bf16)
    u16*   p1    = (u16*)alloc((size_t)2048 * 3072 * 2);       // GEMM1 partial z=1 (bf16)
    u16*   qnb   = (u16*)alloc((size_t)2048 * 2048 * 2);
    u16*   kfrag = (u16*)alloc((size_t)8 * 128 * 1024 * 2);
    u16*   vfrag = (u16*)alloc((size_t)8 * 64 * 2048 * 2);
    u16*   attnb = xb;        // xb dead after GEMM1
    u16*   o2p   = p0;        // p0/p1 dead after norm_rope/v_frag; GEMM2 bf16 partials need 16.8 MB

    cast_bf16_k<<<2048, 256, 0, stream>>>(x, xb, 2048 * 2048 / 4);
    transpose_cast_k<<<dim3(32, 32), 256, 0, stream>>>(wq, wqkvt, 2048, 2048);
    transpose_cast_k<<<dim3(8, 32), 256, 0, stream>>>(wk, wqkvt + (size_t)2048 * 2048, 2048, 512);
    transpose_cast_k<<<dim3(8, 32), 256, 0, stream>>>(wv, wqkvt + (size_t)2560 * 2048, 2048, 512);
    transpose_cast_k<<<dim3(32, 32), 256, 0, stream>>>(wo, wot, 2048, 2048);

    gemm_bt_dbuf_k<<<dim3(24, 16, 2), 256, 0, stream>>>(xb, wqkvt, p0, 2048, 3072, 2048);
    norm_rope_k<<<20480, 256, 0, stream>>>(p0, p1, cosb, sinb, qw, kw, qnb, kfrag);
    v_frag_k<<<dim3(32, 8), 256, 0, stream>>>(p0, p1, vfrag);

    attn_k<<<dim3(32, 128), 64, 0, stream>>>(qnb, kfrag, vfrag, sink, attnb);

    gemm_bt_dbuf_k<<<dim3(16, 16, 2), 256, 0, stream>>>(attnb, wot, o2p, 2048, 2048, 2048);
    sum2_f32_k<<<2048, 256, 0, stream>>>(o2p, o2p + (size_t)2048 * 2048, out, 2048 * 2048 / 8);
}

// Round 12
// 148.659 us; speedup vs baseline: 1.6225x; 1.0051x over previous
//
#include <hip/hip_runtime.h>

typedef unsigned short u16;
typedef __bf16 bf16;
typedef float f32x4 __attribute__((ext_vector_type(4)));
typedef bf16 bf16x8 __attribute__((ext_vector_type(8)));
typedef short s16x4 __attribute__((ext_vector_type(4)));
typedef u16 u16x4 __attribute__((ext_vector_type(4)));
typedef u16 u16x8 __attribute__((ext_vector_type(8)));

#define SEQ 2048
#define LOG2E 1.4426950408889634f

__device__ __forceinline__ u16 f2bf(float f) {
    return __builtin_bit_cast(u16, (bf16)f);
}
__device__ __forceinline__ float bf2f(u16 u) {
    unsigned int w = ((unsigned int)u) << 16;
    return __builtin_bit_cast(float, w);
}

// ---------------- cast f32 -> bf16 (vectorized) ----------------
__global__ __launch_bounds__(256) void cast_bf16_k(const float* __restrict__ in,
                                                   u16* __restrict__ out, int n4) {
    int i = blockIdx.x * 256 + threadIdx.x;
    int stride = gridDim.x * 256;
    for (; i < n4; i += stride) {
        float4 v = reinterpret_cast<const float4*>(in)[i];
        u16x4 o;
        o[0] = f2bf(v.x); o[1] = f2bf(v.y); o[2] = f2bf(v.z); o[3] = f2bf(v.w);
        reinterpret_cast<u16x4*>(out)[i] = o;
    }
}

// ---------------- transpose + cast: src f32 [R][C] -> dst bf16 [C][R] ----------------
__global__ __launch_bounds__(256) void transpose_cast_k(const float* __restrict__ src,
                                                        u16* __restrict__ dst, int R, int C) {
    __shared__ float t[64][65];
    int c0 = blockIdx.x * 64, r0 = blockIdx.y * 64;
    int tx = threadIdx.x & 63, ty = threadIdx.x >> 6;
#pragma unroll
    for (int i = 0; i < 16; ++i) {
        int r = ty + i * 4;
        t[r][tx] = src[(size_t)(r0 + r) * C + c0 + tx];
    }
    __syncthreads();
#pragma unroll
    for (int i = 0; i < 16; ++i) {
        int c = ty + i * 4;
        dst[(size_t)(c0 + c) * R + r0 + tx] = f2bf(t[tx][c]);
    }
}

// ---------------- GEMM partial: Cp[z][M,N](bf16) = A[M,kz] @ Bt[N,kz]^T ----------------
// 128x128 tile, BK=32, split-K (blockIdx.z), double-buffered LDS with prefetch,
// XOR-swizzled LDS slots (pre-swizzled gload_lds source + swizzled ds_read; rule #21).
__global__ __launch_bounds__(256) void gemm_bt_dbuf_k(const u16* __restrict__ A,
                                                      const u16* __restrict__ Bt,
                                                      u16* __restrict__ Cp,
                                                      int M, int N, int K) {
    __shared__ __align__(16) u16 As[2][128 * 32];
    __shared__ __align__(16) u16 Bs[2][128 * 32];
    int tid = threadIdx.x;
    int wave = tid >> 6, lane = tid & 63;
    int bm = blockIdx.y * 128, bn = blockIdx.x * 128;
    int z = blockIdx.z;
    int kt0 = z * (K >> 1), ktend = kt0 + (K >> 1);
    int wm = (wave >> 1) * 64, wn = (wave & 1) * 64;
    int g = lane >> 4, cidx = lane & 15;
    f32x4 acc[4][4] = {};

    // staging: LDS slot (srow, lane&3) holds global k-chunk (lane&3) ^ ((srow>>1)&3)
    int srow = lane >> 2;
    int skol = ((lane & 3) ^ ((srow >> 1) & 3)) * 8;
    // read: logical chunk g of row r lives at slot g ^ ((r_in16>>1)&3); r_in16 = cidx
    int sl8 = (g ^ ((cidx >> 1) & 3)) * 8;

#define STAGE(buf, kt)                                                                \
    {                                                                                 \
        _Pragma("unroll")                                                             \
        for (int j = 0; j < 2; ++j) {                                                 \
            const u16* gpa = A + (size_t)(bm + (wave * 2 + j) * 16 + srow) * K + (kt) + skol; \
            __builtin_amdgcn_global_load_lds(                                         \
                (__attribute__((address_space(1))) void*)gpa,                         \
                (__attribute__((address_space(3))) void*)&As[buf][(wave * 2 + j) * 512], \
                16, 0, 0);                                                            \
        }                                                                             \
        _Pragma("unroll")                                                             \
        for (int j = 0; j < 2; ++j) {                                                 \
            const u16* gpb = Bt + (size_t)(bn + (wave * 2 + j) * 16 + srow) * K + (kt) + skol; \
            __builtin_amdgcn_global_load_lds(                                         \
                (__attribute__((address_space(1))) void*)gpb,                         \
                (__attribute__((address_space(3))) void*)&Bs[buf][(wave * 2 + j) * 512], \
                16, 0, 0);                                                            \
        }                                                                             \
    }

    STAGE(0, kt0);
    asm volatile("s_waitcnt vmcnt(0)" ::: "memory");
    __syncthreads();

    int cur = 0;
#pragma unroll 1
    for (int kt = kt0; kt < ktend; kt += 32) {
        if (kt + 32 < ktend) STAGE(cur ^ 1, kt + 32);  // prefetch in flight across compute

        bf16x8 af[4], bfr[4];
#pragma unroll
        for (int mi = 0; mi < 4; ++mi)
            af[mi] = *reinterpret_cast<const bf16x8*>(&As[cur][(wm + mi * 16 + cidx) * 32 + sl8]);
#pragma unroll
        for (int ni = 0; ni < 4; ++ni)
            bfr[ni] = *reinterpret_cast<const bf16x8*>(&Bs[cur][(wn + ni * 16 + cidx) * 32 + sl8]);
#pragma unroll
        for (int mi = 0; mi < 4; ++mi)
#pragma unroll
            for (int ni = 0; ni < 4; ++ni)
                acc[mi][ni] = __builtin_amdgcn_mfma_f32_16x16x32_bf16(af[mi], bfr[ni], acc[mi][ni], 0, 0, 0);

        asm volatile("s_waitcnt vmcnt(0)" ::: "memory");
        __syncthreads();
        cur ^= 1;
    }
#undef STAGE

    u16* cbase = Cp + (size_t)z * M * N;
#pragma unroll
    for (int mi = 0; mi < 4; ++mi) {
#pragma unroll
        for (int r = 0; r < 4; ++r) {
            int row = bm + wm + mi * 16 + g * 4 + r;
            u16* cp = cbase + (size_t)row * N + bn + wn + cidx;
#pragma unroll
            for (int ni = 0; ni < 4; ++ni)
                cp[ni * 16] = f2bf(acc[mi][ni][r]);
        }
    }
}

// ---------------- sum two bf16 partials -> f32 ----------------
__global__ __launch_bounds__(256) void sum2_f32_k(const u16* __restrict__ a,
                                                  const u16* __restrict__ b,
                                                  float* __restrict__ out, int n8) {
    int i = blockIdx.x * 256 + threadIdx.x;
    if (i >= n8) return;
    u16x8 va = reinterpret_cast<const u16x8*>(a)[i];
    u16x8 vb = reinterpret_cast<const u16x8*>(b)[i];
    f32x4 lo, hi;
#pragma unroll
    for (int j = 0; j < 4; ++j) {
        lo[j] = bf2f(va[j]) + bf2f(vb[j]);
        hi[j] = bf2f(va[4 + j]) + bf2f(vb[4 + j]);
    }
    reinterpret_cast<f32x4*>(out)[i * 2] = lo;
    reinterpret_cast<f32x4*>(out)[i * 2 + 1] = hi;
}

// ---------------- RMSNorm + RoPE for Q and K heads (sums split-K partials) ----------------
// Q: pre-scaled by 0.125*log2(e) (exp2-base softmax), row-major [s][32*64]
// K: MFMA A-fragment order with PERMUTED key placement inside each 32-key group:
//   k32 -> phys (sub = bit2, row = (k32>>3)*4 + (k32&3)); this makes two QK 16-subs
//   concatenate into a K=32 PV B-fragment (lane g holds keys g*8..g*8+7).
__global__ __launch_bounds__(256) void norm_rope_k(const u16* __restrict__ p0,
                                                   const u16* __restrict__ p1,
                                                   const float* __restrict__ cosb,
                                                   const float* __restrict__ sinb,
                                                   const float* __restrict__ qw,
                                                   const float* __restrict__ kw,
                                                   u16* __restrict__ qn,
                                                   u16* __restrict__ kfrag) {
    int idx = blockIdx.x * 4 + (threadIdx.x >> 6);
    int lane = threadIdx.x & 63;
    int s = idx / 40, hh = idx - s * 40;
    size_t off = (hh < 32) ? ((size_t)s * 3072 + hh * 64 + lane)
                           : ((size_t)s * 3072 + 2048 + (hh - 32) * 64 + lane);
    float val = bf2f(p0[off]) + bf2f(p1[off]);
    float ss = val * val;
#pragma unroll
    for (int mm = 32; mm; mm >>= 1) ss += __shfl_xor(ss, mm);
    float w = (hh < 32) ? qw[lane] : kw[lane];
    float xn = val * rsqrtf(ss * (1.f / 64.f) + 1e-6f) * w;
    float part = __shfl_xor(xn, 32);
    float rot = (lane < 32) ? -part : part;
    float o = xn * cosb[s * 64 + lane] + rot * sinb[s * 64 + lane];
    if (hh < 32) {
        qn[(size_t)s * 2048 + hh * 64 + lane] = f2bf(o * (0.125f * LOG2E));
    } else {
        int h8 = hh - 32;
        int k32 = s & 31;
        int p32 = ((k32 >> 2) & 1) * 16 + ((k32 >> 3) << 2) + (k32 & 3);
        int p = (s & ~31) + p32;
        kfrag[(((size_t)h8 * 128 + (p >> 4)) << 10) + (lane >> 3) * 128 + (p & 15) * 8 + (lane & 7)] = f2bf(o);
    }
}

// ---------------- V in K=32 PV A-fragment order ----------------
// vfrag[kvh][kb32][dt][lane(g*16+cc)][i] = V[kb32*32 + g*8 + i][dt*16 + cc]
__global__ __launch_bounds__(256) void v_frag_k(const u16* __restrict__ p0,
                                                const u16* __restrict__ p1,
                                                u16* __restrict__ vfrag) {
    __shared__ float t[64][65];
    int s0 = blockIdx.x * 64;
    int h = blockIdx.y;
    int tx = threadIdx.x & 63, ty = threadIdx.x >> 6;
#pragma unroll
    for (int i = 0; i < 16; ++i) {
        int r = ty + i * 4;
        size_t off = (size_t)(s0 + r) * 3072 + 2560 + h * 64 + tx;
        t[r][tx] = bf2f(p0[off]) + bf2f(p1[off]);
    }
    __syncthreads();
    int dt = threadIdx.x >> 6, g = (threadIdx.x >> 4) & 3, cc = threadIdx.x & 15;
#pragma unroll
    for (int kb = 0; kb < 2; ++kb) {
        u16x8 o;
#pragma unroll
        for (int i = 0; i < 8; ++i) o[i] = f2bf(t[kb * 32 + g * 8 + i][dt * 16 + cc]);
        *reinterpret_cast<u16x8*>(
            &vfrag[((size_t)h * 64 + (s0 >> 5) + kb) * 2048 + dt * 512 + (size_t)(threadIdx.x & 63) * 8]) = o;
    }
}

// ---------------- Flash attention: 32 q-rows/wave, shared K/V, sequential streams ----------------
// 1-wave blocks; wave owns chunks c=2t (A) and c=2t+1 (B) over key-window w (512 keys,
// <=8 iterations -> no long critical path). Per 64-key iteration: load K+V ONCE, then
// A's QK->softmax->PV followed by B's (SEQUENTIAL register lifetime for st/pb -- R9's
// interleaved version spilled ~190 regs; this peaks ~145 under the (64,3) cap ~170).
// Halves memory-path bytes per FLOP vs 16-row waves (the R7-R11 invariant bottleneck).
// item -> (t,w): R9's 160-item mapping; partial o (bf16) + l slots, merged by merge_k.
// NOTE: VGPR caps: (256,8)->32 regs spilled 1.3GB (R4); interleaved dual-stream ~190
// regs spilled (R9). Tripwire: FETCH/WRITE >> 30MB means spill.
__global__ __launch_bounds__(64, 3) void attn_k(const u16* __restrict__ qn,
                                                const u16* __restrict__ kfrag,
                                                const u16* __restrict__ vfrag,
                                                u16* __restrict__ obuf,
                                                float* __restrict__ lbuf) {
    int h = blockIdx.x;
    int kvh = h >> 2;
    int lane = threadIdx.x;
    int item = 159 - blockIdx.y;   // reversed: 4-window pairs (most iters) first
    int t, w;
    if (item < 16)      { t = item;                    w = 0; }
    else if (item < 48) { t = 16 + ((item - 16) >> 1); w = (item - 16) & 1; }
    else if (item < 96) { int r = item - 48; int q = r / 3; t = 32 + q; w = r - 3 * q; }
    else                { t = 48 + ((item - 96) >> 2); w = (item - 96) & 3; }

    int qA0 = t * 32;          // chunk 2t   rows [qA0, qA0+16)
    int qB0 = qA0 + 16;        // chunk 2t+1 rows [qB0, qB0+16)
    int kv0 = w * 512;
    int nkA = qA0 + 16, nkB = qB0 + 16;
    int kvend = (kv0 + 512 < nkB) ? (kv0 + 512) : nkB;

    int g = lane >> 4, cc = lane & 15;
    int qrowA = qA0 + cc, qrowB = qB0 + cc;

    const size_t qoffA = (size_t)qrowA * 2048 + h * 64;
    const size_t qoffB = (size_t)qrowB * 2048 + h * 64;
    bf16x8 qa0 = *reinterpret_cast<const bf16x8*>(&qn[qoffA + g * 8]);
    bf16x8 qa1 = *reinterpret_cast<const bf16x8*>(&qn[qoffA + 32 + g * 8]);
    bf16x8 qb0 = *reinterpret_cast<const bf16x8*>(&qn[qoffB + g * 8]);
    bf16x8 qb1 = *reinterpret_cast<const bf16x8*>(&qn[qoffB + 32 + g * 8]);

    float lA = 0.f, lB = 0.f;
    f32x4 oA[4] = {}, oB[4] = {};

    const u16* kbase = kfrag + (((size_t)kvh * 128) << 10) + lane * 8;
    const u16* vbase = vfrag + (size_t)kvh * 64 * 2048 + lane * 8;

#pragma unroll 1
    for (; kv0 < kvend; kv0 += 64) {
        // K + V loads for this block (one set, shared by both streams)
        bf16x8 kf0[4], kf1[4], vv[2][4];
#pragma unroll
        for (int sub = 0; sub < 4; ++sub) {
            const u16* kp = kbase + (size_t)((kv0 >> 4) + sub) * 1024;
            kf0[sub] = *reinterpret_cast<const bf16x8*>(kp);
            kf1[sub] = *reinterpret_cast<const bf16x8*>(kp + 512);
        }
#pragma unroll
        for (int sp = 0; sp < 2; ++sp)
#pragma unroll
            for (int dt = 0; dt < 4; ++dt)
                vv[sp][dt] = *reinterpret_cast<const bf16x8*>(
                    vbase + (size_t)((kv0 >> 5) + sp) * 2048 + dt * 512);

        bool doA = kv0 < nkA;   // wave-uniform: A's range is 32 keys shorter

        // ---- stream A (st/pb live only in this span) ----
        if (doA) {
            f32x4 st[4];
            __builtin_amdgcn_s_setprio(1);
#pragma unroll
            for (int sub = 0; sub < 4; ++sub) {
                st[sub] = __builtin_amdgcn_mfma_f32_16x16x32_bf16(kf0[sub], qa0, (f32x4){0.f, 0.f, 0.f, 0.f}, 0, 0, 0);
                st[sub] = __builtin_amdgcn_mfma_f32_16x16x32_bf16(kf1[sub], qa1, st[sub], 0, 0, 0);
            }
            __builtin_amdgcn_s_setprio(0);
            if (kv0 + 64 > qA0) {
#pragma unroll
                for (int sub = 0; sub < 4; ++sub)
#pragma unroll
                    for (int r = 0; r < 4; ++r) {
                        int key = kv0 + (sub >> 1) * 32 + g * 8 + (sub & 1) * 4 + r;
                        if (key > qrowA) st[sub][r] = -1e30f;
                    }
            }
            u16x8 pb[2];
            float rs = 0.f;
#pragma unroll
            for (int sub = 0; sub < 4; ++sub)
#pragma unroll
                for (int r = 0; r < 4; ++r) {
                    float e = __builtin_amdgcn_exp2f(st[sub][r]);
                    rs += e;
                    pb[sub >> 1][(sub & 1) * 4 + r] = f2bf(e);
                }
            lA += rs;
            __builtin_amdgcn_s_setprio(1);
#pragma unroll
            for (int sp = 0; sp < 2; ++sp) {
                bf16x8 pbb = __builtin_bit_cast(bf16x8, pb[sp]);
#pragma unroll
                for (int dt = 0; dt < 4; ++dt)
                    oA[dt] = __builtin_amdgcn_mfma_f32_16x16x32_bf16(vv[sp][dt], pbb, oA[dt], 0, 0, 0);
            }
            __builtin_amdgcn_s_setprio(0);
        }

        // ---- stream B ----
        {
            f32x4 st[4];
            __builtin_amdgcn_s_setprio(1);
#pragma unroll
            for (int sub = 0; sub < 4; ++sub) {
                st[sub] = __builtin_amdgcn_mfma_f32_16x16x32_bf16(kf0[sub], qb0, (f32x4){0.f, 0.f, 0.f, 0.f}, 0, 0, 0);
                st[sub] = __builtin_amdgcn_mfma_f32_16x16x32_bf16(kf1[sub], qb1, st[sub], 0, 0, 0);
            }
            __builtin_amdgcn_s_setprio(0);
            if (kv0 + 64 > qB0) {
#pragma unroll
                for (int sub = 0; sub < 4; ++sub)
#pragma unroll
                    for (int r = 0; r < 4; ++r) {
                        int key = kv0 + (sub >> 1) * 32 + g * 8 + (sub & 1) * 4 + r;
                        if (key > qrowB) st[sub][r] = -1e30f;
                    }
            }
            u16x8 pb[2];
            float rs = 0.f;
#pragma unroll
            for (int sub = 0; sub < 4; ++sub)
#pragma unroll
                for (int r = 0; r < 4; ++r) {
                    float e = __builtin_amdgcn_exp2f(st[sub][r]);
                    rs += e;
                    pb[sub >> 1][(sub & 1) * 4 + r] = f2bf(e);
                }
            lB += rs;
            __builtin_amdgcn_s_setprio(1);
#pragma unroll
            for (int sp = 0; sp < 2; ++sp) {
                bf16x8 pbb = __builtin_bit_cast(bf16x8, pb[sp]);
#pragma unroll
                for (int dt = 0; dt < 4; ++dt)
                    oB[dt] = __builtin_amdgcn_mfma_f32_16x16x32_bf16(vv[sp][dt], pbb, oB[dt], 0, 0, 0);
            }
            __builtin_amdgcn_s_setprio(0);
        }
    }

    // private-slot partial writes (plain stores, no atomics); slot = (h*160+item)*2+half
    lA += __shfl_xor(lA, 16);
    lA += __shfl_xor(lA, 32);
    lB += __shfl_xor(lB, 16);
    lB += __shfl_xor(lB, 32);
    size_t slotA = ((size_t)h * 160 + item) * 2;
    if (lane < 16) {
        lbuf[slotA * 16 + cc] = lA;
        lbuf[(slotA + 1) * 16 + cc] = lB;
    }
    u16* spA = obuf + slotA * 1024;
    u16* spB = obuf + (slotA + 1) * 1024;
#pragma unroll
    for (int dt = 0; dt < 4; ++dt) {
        u16x4 ovA, ovB;
#pragma unroll
        for (int r = 0; r < 4; ++r) {
            ovA[r] = f2bf(oA[dt][r]);
            ovB[r] = f2bf(oB[dt][r]);
        }
        *reinterpret_cast<u16x4*>(&spA[cc * 64 + dt * 16 + g * 4]) = ovA;
        *reinterpret_cast<u16x4*>(&spB[cc * 64 + dt * 16 + g * 4]) = ovB;
    }
}

// ---------------- merge: attn_bf16 = sum(o_w) / (sum(l_w) + 2^(sink*log2e)) ----------------
__global__ __launch_bounds__(256) void merge_k(const u16* __restrict__ obuf,
                                               const float* __restrict__ lbuf,
                                               const float* __restrict__ sink,
                                               u16* __restrict__ attnb) {
    int row = blockIdx.x;
    int c = row >> 4, cc = row & 15;
    int t2 = c >> 1, half = c & 1;
    int nw = (t2 >> 4) + 1;  // windows for this 32-row pair
    int jb = (t2 < 16) ? t2
           : (t2 < 32) ? 16 + ((t2 - 16) << 1)
           : (t2 < 48) ? 48 + 3 * (t2 - 32)
                       : 96 + ((t2 - 48) << 2);
    int t = threadIdx.x;
    int h = t >> 3, col0 = (t & 7) * 8;

    float acc[8] = {};
    float lsum = __builtin_amdgcn_exp2f(sink[h] * LOG2E);
#pragma unroll 1
    for (int w = 0; w < nw; ++w) {
        size_t slot = ((size_t)h * 160 + jb + w) * 2 + half;
        lsum += lbuf[slot * 16 + cc];
        u16x8 v = *reinterpret_cast<const u16x8*>(&obuf[slot * 1024 + cc * 64 + col0]);
#pragma unroll
        for (int i = 0; i < 8; ++i) acc[i] += bf2f(v[i]);
    }
    float inv = 1.f / lsum;
    u16x8 ob;
#pragma unroll
    for (int i = 0; i < 8; ++i) ob[i] = f2bf(acc[i] * inv);
    *reinterpret_cast<u16x8*>(&attnb[(size_t)row * 2048 + h * 64 + col0]) = ob;
}

extern "C" void kernel_launch(void* const* d_in, const int* in_sizes, int n_in,
                              void* d_out, int out_size, void* d_ws, size_t ws_size,
                              hipStream_t stream) {
    const float* x    = (const float*)d_in[0];
    const float* cosb = (const float*)d_in[2];
    const float* sinb = (const float*)d_in[3];
    const float* wq   = (const float*)d_in[4];
    const float* wk   = (const float*)d_in[5];
    const float* wv   = (const float*)d_in[6];
    const float* wo   = (const float*)d_in[7];
    const float* qw   = (const float*)d_in[8];
    const float* kw   = (const float*)d_in[9];
    const float* sink = (const float*)d_in[10];
    float* out = (float*)d_out;

    char* ws = (char*)d_ws;
    size_t off = 0;
    auto alloc = [&](size_t bytes) {
        char* p = ws + off;
        off += (bytes + 255) & ~(size_t)255;
        return p;
    };
    u16*   xb    = (u16*)alloc((size_t)2048 * 2048 * 2);       // x bf16
    u16*   wqkvt = (u16*)alloc((size_t)3072 * 2048 * 2);       // [wq^T; wk^T; wv^T]
    u16*   wot   = (u16*)alloc((size_t)2048 * 2048 * 2);       // wo^T
    u16*   p0    = (u16*)alloc((size_t)2048 * 3072 * 2);       // GEMM1 partial z=0 (bf16)
    u16*   p1    = (u16*)alloc((size_t)2048 * 3072 * 2);       // GEMM1 partial z=1 (bf16)
    u16*   qnb   = (u16*)alloc((size_t)2048 * 2048 * 2);
    u16*   kfrag = (u16*)alloc((size_t)8 * 128 * 1024 * 2);
    u16*   vfrag = (u16*)alloc((size_t)8 * 64 * 2048 * 2);
    float* lbuf  = (float*)alloc((size_t)32 * 320 * 16 * 4);
    u16*   attnb = xb;        // xb dead after GEMM1
    u16*   obuf  = p0;        // p0+p1 (25.2 MB contiguous) dead after norm_rope/v_frag; obuf needs 21 MB
    u16*   o2p   = p0;        // obuf dead after merge_k; GEMM2 bf16 partials need 16.8 MB

    cast_bf16_k<<<2048, 256, 0, stream>>>(x, xb, 2048 * 2048 / 4);
    transpose_cast_k<<<dim3(32, 32), 256, 0, stream>>>(wq, wqkvt, 2048, 2048);
    transpose_cast_k<<<dim3(8, 32), 256, 0, stream>>>(wk, wqkvt + (size_t)2048 * 2048, 2048, 512);
    transpose_cast_k<<<dim3(8, 32), 256, 0, stream>>>(wv, wqkvt + (size_t)2560 * 2048, 2048, 512);
    transpose_cast_k<<<dim3(32, 32), 256, 0, stream>>>(wo, wot, 2048, 2048);

    gemm_bt_dbuf_k<<<dim3(24, 16, 2), 256, 0, stream>>>(xb, wqkvt, p0, 2048, 3072, 2048);
    norm_rope_k<<<20480, 256, 0, stream>>>(p0, p1, cosb, sinb, qw, kw, qnb, kfrag);
    v_frag_k<<<dim3(32, 8), 256, 0, stream>>>(p0, p1, vfrag);

    attn_k<<<dim3(32, 160), 64, 0, stream>>>(qnb, kfrag, vfrag, obuf, lbuf);
    merge_k<<<2048, 256, 0, stream>>>(obuf, lbuf, sink, attnb);

    gemm_bt_dbuf_k<<<dim3(16, 16, 2), 256, 0, stream>>>(attnb, wot, o2p, 2048, 2048, 2048);
    sum2_f32_k<<<2048, 256, 0, stream>>>(o2p, o2p + (size_t)2048 * 2048, out, 2048 * 2048 / 8);
}